// Round 7
// baseline (164.286 us; speedup 1.0000x reference)
//
#include <hip/hip_runtime.h>

#define DIMD 512
#define NTOK 2048
#define HEADS 8
#define DH 64

typedef __attribute__((ext_vector_type(4))) float f32x4;
typedef __attribute__((ext_vector_type(8))) __bf16 bf16x8;
typedef __attribute__((ext_vector_type(4))) short s16x4;

#define MFMA16(a, b, c) __builtin_amdgcn_mfma_f32_16x16x32_bf16((a), (b), (c), 0, 0, 0)
#define MFMAK16(a, b, c) __builtin_amdgcn_mfma_f32_16x16x16bf16_1k((a), (b), (c), 0, 0, 0)

__device__ __forceinline__ unsigned short f2bf(float f) {
  unsigned int u = __float_as_uint(f);
  u += 0x7fffu + ((u >> 16) & 1u);
  return (unsigned short)(u >> 16);
}

// raw hardware exp2: one v_exp_f32 (OCML exp2f is a multi-instr denorm-guarded
// sequence without -ffast-math — measured as the dominant attn VALU cost).
// Inputs here are <= -15 (live) or ~-1e5 (masked -> underflows to +0). Both exact.
__device__ __forceinline__ float fexp2(float x) {
  float r;
  asm("v_exp_f32 %0, %1" : "=v"(r) : "v"(x));
  return r;
}

// pack truncated bf16(b) into low short, bf16(a) into high short
__device__ __forceinline__ unsigned packhi(float b, float a) {
#if __has_builtin(__builtin_amdgcn_perm)
  return __builtin_amdgcn_perm(__float_as_uint(a), __float_as_uint(b), 0x07060302u);
#else
  return (__float_as_uint(b) >> 16) | (__float_as_uint(a) & 0xffff0000u);
#endif
}

// async global->LDS, 16B per lane; LDS dest = wave base + lane*16 (contiguous).
__device__ __forceinline__ void gl2lds16(const void* g, void* l) {
  auto gp = reinterpret_cast<__attribute__((address_space(1))) unsigned int*>(
      reinterpret_cast<unsigned long long>(g));
  auto lp = reinterpret_cast<__attribute__((address_space(3))) unsigned int*>(
      reinterpret_cast<unsigned long long>(l));
  __builtin_amdgcn_global_load_lds(gp, lp, 16, 0, 0);
}

// ---------------- prep: LN(bid<2048) + w_qkv transpose + w_out transpose ----------------
__global__ __launch_bounds__(256) void prep_kernel(const float* __restrict__ x,
                                                   const float* __restrict__ gamma,
                                                   const float* __restrict__ beta,
                                                   const float* __restrict__ w_qkv,
                                                   const float* __restrict__ w_out,
                                                   unsigned short* __restrict__ xn,
                                                   unsigned short* __restrict__ wqkvT,
                                                   unsigned short* __restrict__ woutT) {
  __shared__ float t[32][33];
  const int bid = blockIdx.x;
  if (bid < 2048) {
    const int row = bid * 4 + (threadIdx.x >> 6);
    const int lane = threadIdx.x & 63;
    const float4* xr = (const float4*)(x + (size_t)row * DIMD);
    float4 a = xr[lane];
    float4 b = xr[lane + 64];
    float s = a.x + a.y + a.z + a.w + b.x + b.y + b.z + b.w;
    for (int off = 1; off < 64; off <<= 1) s += __shfl_xor(s, off, 64);
    float mu = s * (1.0f / DIMD);
    float d0 = a.x - mu, d1 = a.y - mu, d2 = a.z - mu, d3 = a.w - mu;
    float e0 = b.x - mu, e1 = b.y - mu, e2 = b.z - mu, e3 = b.w - mu;
    float v = d0 * d0 + d1 * d1 + d2 * d2 + d3 * d3 + e0 * e0 + e1 * e1 + e2 * e2 + e3 * e3;
    for (int off = 1; off < 64; off <<= 1) v += __shfl_xor(v, off, 64);
    float rs = rsqrtf(v * (1.0f / DIMD) + 1e-5f);
    const float4* g4 = (const float4*)gamma;
    const float4* be4 = (const float4*)beta;
    float4 ga = g4[lane], gb = g4[lane + 64];
    float4 ba = be4[lane], bb = be4[lane + 64];
    unsigned p0 = (unsigned)f2bf(d0 * rs * ga.x + ba.x) | ((unsigned)f2bf(d1 * rs * ga.y + ba.y) << 16);
    unsigned p1 = (unsigned)f2bf(d2 * rs * ga.z + ba.z) | ((unsigned)f2bf(d3 * rs * ga.w + ba.w) << 16);
    unsigned p2 = (unsigned)f2bf(e0 * rs * gb.x + bb.x) | ((unsigned)f2bf(e1 * rs * gb.y + bb.y) << 16);
    unsigned p3 = (unsigned)f2bf(e2 * rs * gb.z + bb.z) | ((unsigned)f2bf(e3 * rs * gb.w + bb.w) << 16);
    uint2 w0; w0.x = p0; w0.y = p1;
    uint2 w1; w1.x = p2; w1.y = p3;
    *(uint2*)&xn[(size_t)row * DIMD + lane * 4] = w0;
    *(uint2*)&xn[(size_t)row * DIMD + 256 + lane * 4] = w1;
  } else {
    const float* w;
    unsigned short* wt;
    int C, bx, by;
    if (bid < 2816) { w = w_qkv; wt = wqkvT; C = 1536; bx = (bid - 2048) % 48; by = (bid - 2048) / 48; }
    else            { w = w_out; wt = woutT; C = 512;  bx = (bid - 2816) % 16; by = (bid - 2816) / 16; }
    const int R = 512;
    int tx = threadIdx.x & 31, ty = threadIdx.x >> 5;
    int c0 = bx * 32, r0 = by * 32;
    for (int i = 0; i < 4; i++)
      t[ty + 8 * i][tx] = w[(size_t)(r0 + ty + 8 * i) * C + c0 + tx];
    __syncthreads();
    for (int i = 0; i < 4; i++)
      wt[(size_t)(c0 + ty + 8 * i) * R + r0 + tx] = f2bf(t[tx][ty + 8 * i]);
  }
}

// ---------------- QKV GEMM: 128x128 tile, BK=64, swizzled DMA dbuf ----------------
__global__ __launch_bounds__(256, 2) void qkv_gemm(const unsigned short* __restrict__ A,
                                                   const unsigned short* __restrict__ Bt,
                                                   unsigned short* __restrict__ qb,
                                                   unsigned short* __restrict__ kb,
                                                   unsigned short* __restrict__ vtb) {
  __shared__ unsigned short As[2][128 * 64];
  __shared__ unsigned short Bs[2][128 * 64];
  const int tid = threadIdx.x;
  const int wave = tid >> 6, lane = tid & 63;
  const int row16 = lane & 15, quad = lane >> 4;
  const int rho = row16 & 7;
  const int m0 = blockIdx.x * 128;
  const int n0 = blockIdx.y * 128;
  const int rw = (wave & 1) * 64, cw = (wave >> 1) * 64;

  const char* Ab = (const char*)A;
  const char* Bb = (const char*)Bt;
#pragma unroll
  for (int i = 0; i < 4; i++) {
    int idx = i * 256 + tid;
    int r = idx >> 3;
    int c = (idx & 7) ^ (r & 7);
    gl2lds16(Ab + ((size_t)(m0 + r) * DIMD) * 2 + c * 16, (char*)As[0] + idx * 16);
    gl2lds16(Bb + ((size_t)(n0 + r) * DIMD) * 2 + c * 16, (char*)Bs[0] + idx * 16);
  }
  __syncthreads();

  f32x4 acc[4][4] = {};
  for (int kt = 0; kt < 8; kt++) {
    const int buf = kt & 1;
    if (kt < 7) {
      const int k0 = (kt + 1) * 64;
#pragma unroll
      for (int i = 0; i < 4; i++) {
        int idx = i * 256 + tid;
        int r = idx >> 3;
        int c = (idx & 7) ^ (r & 7);
        gl2lds16(Ab + ((size_t)(m0 + r) * DIMD + k0) * 2 + c * 16, (char*)As[buf ^ 1] + idx * 16);
        gl2lds16(Bb + ((size_t)(n0 + r) * DIMD + k0) * 2 + c * 16, (char*)Bs[buf ^ 1] + idx * 16);
      }
    }
#pragma unroll
    for (int ks = 0; ks < 2; ks++) {
      bf16x8 av[4], bv[4];
#pragma unroll
      for (int i = 0; i < 4; i++) {
        int Ra = rw + i * 16 + row16;
        int Rb = cw + i * 16 + row16;
        av[i] = *(const bf16x8*)&As[buf][Ra * 64 + (((ks * 4 + quad) ^ rho) * 8)];
        bv[i] = *(const bf16x8*)&Bs[buf][Rb * 64 + (((ks * 4 + quad) ^ rho) * 8)];
      }
#pragma unroll
      for (int i = 0; i < 4; i++)
#pragma unroll
        for (int j = 0; j < 4; j++) acc[i][j] = MFMA16(av[i], bv[j], acc[i][j]);
    }
    __syncthreads();
  }

  unsigned short* Ct = (unsigned short*)As;
#pragma unroll
  for (int i = 0; i < 4; i++)
#pragma unroll
    for (int j = 0; j < 4; j++)
#pragma unroll
      for (int r = 0; r < 4; r++)
        Ct[(rw + i * 16 + quad * 4 + r) * 136 + cw + j * 16 + row16] = f2bf(acc[i][j][r]);
  __syncthreads();

  const int sect = n0 >> 9;
  const int h0 = (n0 & 511) >> 6;
  const int b = m0 >> 11;
  const int nbase = m0 & 2047;
  if (sect < 2) {
    unsigned short* dst = (sect == 0) ? qb : kb;
#pragma unroll
    for (int i = 0; i < 8; i++) {
      int cid = i * 256 + tid;
      int row = cid >> 4, col0 = (cid & 15) * 8;
      int h = h0 + (col0 >> 6), d0 = col0 & 63;
      uint4 val = *(const uint4*)&Ct[row * 136 + col0];
      *(uint4*)&dst[(((size_t)(b * HEADS + h) * NTOK) + nbase + row) * DH + d0] = val;
    }
  } else {
#pragma unroll
    for (int u = 0; u < 4; u++) {
      int uid = u * 256 + tid;
      int col = uid >> 3, rc = (uid & 7) * 16;
      int h = h0 + (col >> 6), d = col & 63;
      unsigned short tmp[16];
#pragma unroll
      for (int j = 0; j < 16; j++) tmp[j] = Ct[(rc + j) * 136 + col];
      size_t base = ((size_t)(b * HEADS + h) * DH + d) * NTOK + nbase + rc;
      *(uint4*)&vtb[base] = *(uint4*)&tmp[0];
      *(uint4*)&vtb[base + 8] = *(uint4*)&tmp[8];
    }
  }
}

// ---------------- attention: q-tile 256, 4 waves x 64 q-rows, S^T + register PV ----------------
// Pipe audit: MFMA/VALU/LDS each 35-45% busy -> multi-pipe equilibrium. The only axis
// not yet tried in the winning direction: LDS traffic per unit work = 16KB x waves /
// (q-rows). R1 (16w x 32q) doubled traffic -> +12%; two-point fit ~0.048us/KB.
// This config: 4 waves x 64 q-rows/wave: per-CU LDS traffic per tile HALVES (128->64KB),
// conflicts halve, MFMA+VALU per SIMD unchanged, same grid/DMA/barriers, no epilogue
// change (each wave owns complete q-rows -> no cross-wave reduction; R4's trap avoided).
// TLP=1 wave/SIMD: mitigated by __launch_bounds__(256,1) -> 512-VGPR budget, all LDS
// addresses + both tile read-batches hoistable/prefetchable by the compiler.
__global__ __launch_bounds__(256, 1) void attn_kernel(const unsigned short* __restrict__ qb,
                                                      const unsigned short* __restrict__ kb,
                                                      const unsigned short* __restrict__ vtb,
                                                      const int* __restrict__ mlab,
                                                      unsigned short* __restrict__ ao) {
  __shared__ unsigned short Qs[256 * 64];     // 32KB
  __shared__ unsigned short Ks[2][64 * 64];   // 16KB
  __shared__ unsigned short Vs[2][64 * 64];   // 16KB
  const int tid = threadIdx.x;                // 0..255, 4 waves
  const int wave = tid >> 6, lane = tid & 63;
  const int row16 = lane & 15, quad = lane >> 4;
  const int rho = row16 & 7;
  const int bh = blockIdx.x;                  // XCD = id%8 = bh%8 (keeps R6 FETCH win)
  const int b = bh >> 3, h = bh & 7;
  const int q0 = blockIdx.y * 256;

  const char* qg = (const char*)(qb + ((size_t)bh * NTOK + q0) * DH);
  const char* kgb = (const char*)(kb + (size_t)bh * NTOK * DH);
  const char* vgb = (const char*)(vtb + (size_t)bh * DH * NTOK);

  // prologue: Q (256 rows, 32KB = 8 chunks/thread) + K/V tile 0 (2 chunks/thread each)
#pragma unroll
  for (int i = 0; i < 8; i++) {
    int idx = i * 256 + tid;
    int r = idx >> 3;
    int c = (idx & 7) ^ (r & 7);
    gl2lds16(qg + r * 128 + c * 16, (char*)Qs + idx * 16);
  }
#pragma unroll
  for (int i = 0; i < 2; i++) {
    int idx = i * 256 + tid;
    int r = idx >> 3;
    int c = (idx & 7) ^ (r & 7);
    gl2lds16(kgb + r * 128 + c * 16, (char*)Ks[0] + idx * 16);
    gl2lds16(vgb + (size_t)r * 4096 + c * 16, (char*)Vs[0] + idx * 16);
  }
  __syncthreads();

  // wave owns q-rows [wave*64, wave*64+64): 4 q-groups of 16
  bf16x8 aq[4][2];
#pragma unroll
  for (int qg2 = 0; qg2 < 4; qg2++) {
    const int qrow = wave * 64 + qg2 * 16 + row16;
#pragma unroll
    for (int ki = 0; ki < 2; ki++)
      aq[qg2][ki] = *(const bf16x8*)&Qs[qrow * 64 + (((ki * 4 + quad) ^ rho) * 8)];
  }

  f32x4 accT[4][4] = {};  // O^T frags: [d-group][q-group]
  float lsum[4] = {0.f, 0.f, 0.f, 0.f};
  const float cs = 0.125f * 1.44269504088896f;
  const float c0 = mlab[b * 4 + 0] ? -16.f : -100000.f;
  const float c1 = mlab[b * 4 + 1] ? -16.f : -100000.f;
  const float c2 = mlab[b * 4 + 2] ? -16.f : -100000.f;
  const float c3 = mlab[b * 4 + 3] ? -16.f : -100000.f;

  for (int t = 0; t < 32; t++) {
    const int buf = t & 1;
    if (t < 31) {
#pragma unroll
      for (int i = 0; i < 2; i++) {
        int idx = i * 256 + tid;
        int r = idx >> 3;
        int c = (idx & 7) ^ (r & 7);
        gl2lds16(kgb + (size_t)(t + 1) * 8192 + r * 128 + c * 16, (char*)Ks[buf ^ 1] + idx * 16);
        gl2lds16(vgb + (size_t)(t + 1) * 128 + (size_t)r * 4096 + c * 16, (char*)Vs[buf ^ 1] + idx * 16);
      }
    }
    // S'[key][q]: A = K frag, B = Q frag; each wave covers all 64 keys x its 64 q
    f32x4 S[4][4];
#pragma unroll
    for (int f = 0; f < 4; f++) {
      const unsigned short* Kr = &Ks[buf][(f * 16 + row16) * 64];
      bf16x8 ak0 = *(const bf16x8*)&Kr[(quad ^ rho) * 8];
      bf16x8 ak1 = *(const bf16x8*)&Kr[((quad + 4) ^ rho) * 8];
#pragma unroll
      for (int qg2 = 0; qg2 < 4; qg2++) {
        f32x4 z = {};
        z = MFMA16(ak0, aq[qg2][0], z);
        z = MFMA16(ak1, aq[qg2][1], z);
        S[qg2][f] = z;
      }
    }
    const int mi = t >> 3;
    const float c = (mi == 0) ? c0 : (mi == 1) ? c1 : (mi == 2) ? c2 : c3;
    // P' = exp2(S'*cs + c) via raw v_exp_f32; pack into K16 B-operand frags
    s16x4 pf[4][4];
#pragma unroll
    for (int qg2 = 0; qg2 < 4; qg2++)
#pragma unroll
      for (int f = 0; f < 4; f++) {
        float p0 = fexp2(fmaf(S[qg2][f][0], cs, c));
        float p1 = fexp2(fmaf(S[qg2][f][1], cs, c));
        float p2 = fexp2(fmaf(S[qg2][f][2], cs, c));
        float p3 = fexp2(fmaf(S[qg2][f][3], cs, c));
        lsum[qg2] += (p0 + p1) + (p2 + p3);
        uint2 pk;
        pk.x = packhi(p0, p1);
        pk.y = packhi(p2, p3);
        pf[qg2][f] = *(s16x4*)&pk;
      }
    // O^T += V^T · P'
#pragma unroll
    for (int g = 0; g < 4; g++) {
      const unsigned short* Vr = &Vs[buf][(g * 16 + row16) * 64];
#pragma unroll
      for (int u = 0; u < 4; u++) {
        s16x4 va = *(const s16x4*)&Vr[(((2 * u + (quad >> 1)) ^ rho) * 8) + (quad & 1) * 4];
#pragma unroll
        for (int qg2 = 0; qg2 < 4; qg2++) accT[g][qg2] = MFMAK16(va, pf[qg2][u], accT[g][qg2]);
      }
    }
    __syncthreads();
  }

  // lane partial covers its quad's keys; combine across quads (q = qg*16+row16)
#pragma unroll
  for (int qg2 = 0; qg2 < 4; qg2++) {
    float s = lsum[qg2];
    s += __shfl_xor(s, 16, 64);
    s += __shfl_xor(s, 32, 64);
    lsum[qg2] = 1.0f / s;
  }
#pragma unroll
  for (int qg2 = 0; qg2 < 4; qg2++) {
    const int q = q0 + wave * 64 + qg2 * 16 + row16;
    unsigned short* aor = ao + ((size_t)b * NTOK + q) * DIMD + h * DH;
#pragma unroll
    for (int g = 0; g < 4; g++) {
      *(unsigned*)&aor[g * 16 + quad * 4] = packhi(accT[g][qg2][0] * lsum[qg2], accT[g][qg2][1] * lsum[qg2]);
      *(unsigned*)&aor[g * 16 + quad * 4 + 2] = packhi(accT[g][qg2][2] * lsum[qg2], accT[g][qg2][3] * lsum[qg2]);
    }
  }
}

// ---------------- out GEMM: 128x64 tile, DMA dbuf, fp32 out + bias ----------------
__global__ __launch_bounds__(256, 2) void out_gemm(const unsigned short* __restrict__ A,
                                                   const unsigned short* __restrict__ Bt,
                                                   const float* __restrict__ bias,
                                                   float* __restrict__ out) {
  __shared__ unsigned short As[2][128 * 64];
  __shared__ unsigned short Bs[2][64 * 64];
  const int tid = threadIdx.x;
  const int wave = tid >> 6, lane = tid & 63;
  const int row16 = lane & 15, quad = lane >> 4;
  const int rho = row16 & 7;
  const int m0 = blockIdx.x * 128;
  const int n0 = blockIdx.y * 64;
  const int rw = (wave & 1) * 64, cw = (wave >> 1) * 32;

  const char* Ab = (const char*)A;
  const char* Bb = (const char*)Bt;
#pragma unroll
  for (int i = 0; i < 4; i++) {
    int idx = i * 256 + tid;
    int r = idx >> 3;
    int c = (idx & 7) ^ (r & 7);
    gl2lds16(Ab + ((size_t)(m0 + r) * DIMD) * 2 + c * 16, (char*)As[0] + idx * 16);
  }
#pragma unroll
  for (int i = 0; i < 2; i++) {
    int idx = i * 256 + tid;
    int r = idx >> 3;
    int c = (idx & 7) ^ (r & 7);
    gl2lds16(Bb + ((size_t)(n0 + r) * DIMD) * 2 + c * 16, (char*)Bs[0] + idx * 16);
  }
  __syncthreads();

  f32x4 acc[4][2] = {};
  for (int kt = 0; kt < 8; kt++) {
    const int buf = kt & 1;
    if (kt < 7) {
      const int k0 = (kt + 1) * 64;
#pragma unroll
      for (int i = 0; i < 4; i++) {
        int idx = i * 256 + tid;
        int r = idx >> 3;
        int c = (idx & 7) ^ (r & 7);
        gl2lds16(Ab + ((size_t)(m0 + r) * DIMD + k0) * 2 + c * 16, (char*)As[buf ^ 1] + idx * 16);
      }
#pragma unroll
      for (int i = 0; i < 2; i++) {
        int idx = i * 256 + tid;
        int r = idx >> 3;
        int c = (idx & 7) ^ (r & 7);
        gl2lds16(Bb + ((size_t)(n0 + r) * DIMD + k0) * 2 + c * 16, (char*)Bs[buf ^ 1] + idx * 16);
      }
    }
#pragma unroll
    for (int ks = 0; ks < 2; ks++) {
      bf16x8 av[4], bv[2];
#pragma unroll
      for (int i = 0; i < 4; i++)
        av[i] = *(const bf16x8*)&As[buf][(rw + i * 16 + row16) * 64 + (((ks * 4 + quad) ^ rho) * 8)];
#pragma unroll
      for (int j = 0; j < 2; j++)
        bv[j] = *(const bf16x8*)&Bs[buf][(cw + j * 16 + row16) * 64 + (((ks * 4 + quad) ^ rho) * 8)];
#pragma unroll
      for (int i = 0; i < 4; i++)
#pragma unroll
        for (int j = 0; j < 2; j++) acc[i][j] = MFMA16(av[i], bv[j], acc[i][j]);
    }
    __syncthreads();
  }

#pragma unroll
  for (int j = 0; j < 2; j++) {
    const int col = n0 + cw + j * 16 + row16;
    const float bv = bias[col];
#pragma unroll
    for (int i = 0; i < 4; i++)
#pragma unroll
      for (int r = 0; r < 4; r++) {
        const int row = m0 + rw + i * 16 + quad * 4 + r;
        out[(size_t)row * DIMD + col] = acc[i][j][r] + bv;
      }
  }
}

extern "C" void kernel_launch(void* const* d_in, const int* in_sizes, int n_in,
                              void* d_out, int out_size, void* d_ws, size_t ws_size,
                              hipStream_t stream) {
  const float* x = (const float*)d_in[0];
  const int* mlab = (const int*)d_in[1];
  const float* gamma = (const float*)d_in[2];
  const float* beta = (const float*)d_in[3];
  const float* w_qkv = (const float*)d_in[4];
  const float* w_out = (const float*)d_in[5];
  const float* b_out = (const float*)d_in[6];
  float* out = (float*)d_out;

  char* ws = (char*)d_ws;
  unsigned short* xn = (unsigned short*)(ws);
  unsigned short* wqkvT = (unsigned short*)(ws + 8388608);
  unsigned short* woutT = (unsigned short*)(ws + 9961472);
  unsigned short* qbuf = (unsigned short*)(ws + 10485760);
  unsigned short* kbuf = (unsigned short*)(ws + 18874368);
  unsigned short* vtbuf = (unsigned short*)(ws + 27262976);
  unsigned short* aobuf = (unsigned short*)(ws + 35651584);

  prep_kernel<<<3072, 256, 0, stream>>>(x, gamma, beta, w_qkv, w_out, xn, wqkvT, woutT);
  qkv_gemm<<<dim3(64, 12), 256, 0, stream>>>(xn, wqkvT, qbuf, kbuf, vtbuf);
  attn_kernel<<<dim3(32, 8), 256, 0, stream>>>(qbuf, kbuf, vtbuf, mlab, aobuf);
  out_gemm<<<dim3(64, 8), 256, 0, stream>>>(aobuf, woutT, b_out, out);
}

// Round 8
// 153.674 us; speedup vs baseline: 1.0691x; 1.0691x over previous
//
#include <hip/hip_runtime.h>

#define DIMD 512
#define NTOK 2048
#define HEADS 8
#define DH 64

typedef __attribute__((ext_vector_type(4))) float f32x4;
typedef __attribute__((ext_vector_type(8))) __bf16 bf16x8;
typedef __attribute__((ext_vector_type(4))) short s16x4;

#define MFMA16(a, b, c) __builtin_amdgcn_mfma_f32_16x16x32_bf16((a), (b), (c), 0, 0, 0)
#define MFMAK16(a, b, c) __builtin_amdgcn_mfma_f32_16x16x16bf16_1k((a), (b), (c), 0, 0, 0)

__device__ __forceinline__ unsigned short f2bf(float f) {
  unsigned int u = __float_as_uint(f);
  u += 0x7fffu + ((u >> 16) & 1u);
  return (unsigned short)(u >> 16);
}

// raw hardware exp2: one v_exp_f32 (OCML exp2f is a multi-instr denorm-guarded
// sequence without -ffast-math — measured as the dominant attn VALU cost).
// Inputs here are <= -15 (live) or ~-1e5 (masked -> underflows to +0). Both exact.
__device__ __forceinline__ float fexp2(float x) {
  float r;
  asm("v_exp_f32 %0, %1" : "=v"(r) : "v"(x));
  return r;
}

// pack truncated bf16(b) into low short, bf16(a) into high short
__device__ __forceinline__ unsigned packhi(float b, float a) {
#if __has_builtin(__builtin_amdgcn_perm)
  return __builtin_amdgcn_perm(__float_as_uint(a), __float_as_uint(b), 0x07060302u);
#else
  return (__float_as_uint(b) >> 16) | (__float_as_uint(a) & 0xffff0000u);
#endif
}

// async global->LDS, 16B per lane; LDS dest = wave base + lane*16 (contiguous).
__device__ __forceinline__ void gl2lds16(const void* g, void* l) {
  auto gp = reinterpret_cast<__attribute__((address_space(1))) unsigned int*>(
      reinterpret_cast<unsigned long long>(g));
  auto lp = reinterpret_cast<__attribute__((address_space(3))) unsigned int*>(
      reinterpret_cast<unsigned long long>(l));
  __builtin_amdgcn_global_load_lds(gp, lp, 16, 0, 0);
}

// ---------------- prep: LN(bid<2048) + w_qkv transpose + w_out transpose ----------------
__global__ __launch_bounds__(256) void prep_kernel(const float* __restrict__ x,
                                                   const float* __restrict__ gamma,
                                                   const float* __restrict__ beta,
                                                   const float* __restrict__ w_qkv,
                                                   const float* __restrict__ w_out,
                                                   unsigned short* __restrict__ xn,
                                                   unsigned short* __restrict__ wqkvT,
                                                   unsigned short* __restrict__ woutT) {
  __shared__ float t[32][33];
  const int bid = blockIdx.x;
  if (bid < 2048) {
    const int row = bid * 4 + (threadIdx.x >> 6);
    const int lane = threadIdx.x & 63;
    const float4* xr = (const float4*)(x + (size_t)row * DIMD);
    float4 a = xr[lane];
    float4 b = xr[lane + 64];
    float s = a.x + a.y + a.z + a.w + b.x + b.y + b.z + b.w;
    for (int off = 1; off < 64; off <<= 1) s += __shfl_xor(s, off, 64);
    float mu = s * (1.0f / DIMD);
    float d0 = a.x - mu, d1 = a.y - mu, d2 = a.z - mu, d3 = a.w - mu;
    float e0 = b.x - mu, e1 = b.y - mu, e2 = b.z - mu, e3 = b.w - mu;
    float v = d0 * d0 + d1 * d1 + d2 * d2 + d3 * d3 + e0 * e0 + e1 * e1 + e2 * e2 + e3 * e3;
    for (int off = 1; off < 64; off <<= 1) v += __shfl_xor(v, off, 64);
    float rs = rsqrtf(v * (1.0f / DIMD) + 1e-5f);
    const float4* g4 = (const float4*)gamma;
    const float4* be4 = (const float4*)beta;
    float4 ga = g4[lane], gb = g4[lane + 64];
    float4 ba = be4[lane], bb = be4[lane + 64];
    unsigned p0 = (unsigned)f2bf(d0 * rs * ga.x + ba.x) | ((unsigned)f2bf(d1 * rs * ga.y + ba.y) << 16);
    unsigned p1 = (unsigned)f2bf(d2 * rs * ga.z + ba.z) | ((unsigned)f2bf(d3 * rs * ga.w + ba.w) << 16);
    unsigned p2 = (unsigned)f2bf(e0 * rs * gb.x + bb.x) | ((unsigned)f2bf(e1 * rs * gb.y + bb.y) << 16);
    unsigned p3 = (unsigned)f2bf(e2 * rs * gb.z + bb.z) | ((unsigned)f2bf(e3 * rs * gb.w + bb.w) << 16);
    uint2 w0; w0.x = p0; w0.y = p1;
    uint2 w1; w1.x = p2; w1.y = p3;
    *(uint2*)&xn[(size_t)row * DIMD + lane * 4] = w0;
    *(uint2*)&xn[(size_t)row * DIMD + 256 + lane * 4] = w1;
  } else {
    const float* w;
    unsigned short* wt;
    int C, bx, by;
    if (bid < 2816) { w = w_qkv; wt = wqkvT; C = 1536; bx = (bid - 2048) % 48; by = (bid - 2048) / 48; }
    else            { w = w_out; wt = woutT; C = 512;  bx = (bid - 2816) % 16; by = (bid - 2816) / 16; }
    const int R = 512;
    int tx = threadIdx.x & 31, ty = threadIdx.x >> 5;
    int c0 = bx * 32, r0 = by * 32;
    for (int i = 0; i < 4; i++)
      t[ty + 8 * i][tx] = w[(size_t)(r0 + ty + 8 * i) * C + c0 + tx];
    __syncthreads();
    for (int i = 0; i < 4; i++)
      wt[(size_t)(c0 + ty + 8 * i) * R + r0 + tx] = f2bf(t[tx][ty + 8 * i]);
  }
}

// ---------------- QKV GEMM: 128x128 tile, BK=64, swizzled DMA dbuf ----------------
__global__ __launch_bounds__(256, 2) void qkv_gemm(const unsigned short* __restrict__ A,
                                                   const unsigned short* __restrict__ Bt,
                                                   unsigned short* __restrict__ qb,
                                                   unsigned short* __restrict__ kb,
                                                   unsigned short* __restrict__ vtb) {
  __shared__ unsigned short As[2][128 * 64];
  __shared__ unsigned short Bs[2][128 * 64];
  const int tid = threadIdx.x;
  const int wave = tid >> 6, lane = tid & 63;
  const int row16 = lane & 15, quad = lane >> 4;
  const int rho = row16 & 7;
  const int m0 = blockIdx.x * 128;
  const int n0 = blockIdx.y * 128;
  const int rw = (wave & 1) * 64, cw = (wave >> 1) * 64;

  const char* Ab = (const char*)A;
  const char* Bb = (const char*)Bt;
#pragma unroll
  for (int i = 0; i < 4; i++) {
    int idx = i * 256 + tid;
    int r = idx >> 3;
    int c = (idx & 7) ^ (r & 7);
    gl2lds16(Ab + ((size_t)(m0 + r) * DIMD) * 2 + c * 16, (char*)As[0] + idx * 16);
    gl2lds16(Bb + ((size_t)(n0 + r) * DIMD) * 2 + c * 16, (char*)Bs[0] + idx * 16);
  }
  __syncthreads();

  f32x4 acc[4][4] = {};
  for (int kt = 0; kt < 8; kt++) {
    const int buf = kt & 1;
    if (kt < 7) {
      const int k0 = (kt + 1) * 64;
#pragma unroll
      for (int i = 0; i < 4; i++) {
        int idx = i * 256 + tid;
        int r = idx >> 3;
        int c = (idx & 7) ^ (r & 7);
        gl2lds16(Ab + ((size_t)(m0 + r) * DIMD + k0) * 2 + c * 16, (char*)As[buf ^ 1] + idx * 16);
        gl2lds16(Bb + ((size_t)(n0 + r) * DIMD + k0) * 2 + c * 16, (char*)Bs[buf ^ 1] + idx * 16);
      }
    }
#pragma unroll
    for (int ks = 0; ks < 2; ks++) {
      bf16x8 av[4], bv[4];
#pragma unroll
      for (int i = 0; i < 4; i++) {
        int Ra = rw + i * 16 + row16;
        int Rb = cw + i * 16 + row16;
        av[i] = *(const bf16x8*)&As[buf][Ra * 64 + (((ks * 4 + quad) ^ rho) * 8)];
        bv[i] = *(const bf16x8*)&Bs[buf][Rb * 64 + (((ks * 4 + quad) ^ rho) * 8)];
      }
#pragma unroll
      for (int i = 0; i < 4; i++)
#pragma unroll
        for (int j = 0; j < 4; j++) acc[i][j] = MFMA16(av[i], bv[j], acc[i][j]);
    }
    __syncthreads();
  }

  unsigned short* Ct = (unsigned short*)As;
#pragma unroll
  for (int i = 0; i < 4; i++)
#pragma unroll
    for (int j = 0; j < 4; j++)
#pragma unroll
      for (int r = 0; r < 4; r++)
        Ct[(rw + i * 16 + quad * 4 + r) * 136 + cw + j * 16 + row16] = f2bf(acc[i][j][r]);
  __syncthreads();

  const int sect = n0 >> 9;
  const int h0 = (n0 & 511) >> 6;
  const int b = m0 >> 11;
  const int nbase = m0 & 2047;
  if (sect < 2) {
    unsigned short* dst = (sect == 0) ? qb : kb;
#pragma unroll
    for (int i = 0; i < 8; i++) {
      int cid = i * 256 + tid;
      int row = cid >> 4, col0 = (cid & 15) * 8;
      int h = h0 + (col0 >> 6), d0 = col0 & 63;
      uint4 val = *(const uint4*)&Ct[row * 136 + col0];
      *(uint4*)&dst[(((size_t)(b * HEADS + h) * NTOK) + nbase + row) * DH + d0] = val;
    }
  } else {
#pragma unroll
    for (int u = 0; u < 4; u++) {
      int uid = u * 256 + tid;
      int col = uid >> 3, rc = (uid & 7) * 16;
      int h = h0 + (col >> 6), d = col & 63;
      unsigned short tmp[16];
#pragma unroll
      for (int j = 0; j < 16; j++) tmp[j] = Ct[(rc + j) * 136 + col];
      size_t base = ((size_t)(b * HEADS + h) * DH + d) * NTOK + nbase + rc;
      *(uint4*)&vtb[base] = *(uint4*)&tmp[0];
      *(uint4*)&vtb[base + 8] = *(uint4*)&tmp[8];
    }
  }
}

// ---------------- attention: q-tile 256, 16 waves = 8 qw x 2 kw (key-split) ----------------
// R1 vs R7 bracket: TLP covers the serial chain, but TLP must not multiply LDS traffic.
// This config: wave (qw,kw) owns 32 q-rows (baseline amount) and HALF the keys ->
// per-SIMD pipe totals (MFMA/VALU/LDS bytes) identical to the 8-wave baseline, but
// 4 waves/SIMD instead of 2. Epilogue: R4's verified cross-kw reduction (~4us).
// Staging: waves 0-7 DMA K, 8-15 DMA V (1 gl2lds16/thread/tile). LDS 64KB -> 1 blk/CU.
__global__ __launch_bounds__(1024, 4) void attn_kernel(const unsigned short* __restrict__ qb,
                                                       const unsigned short* __restrict__ kb,
                                                       const unsigned short* __restrict__ vtb,
                                                       const int* __restrict__ mlab,
                                                       unsigned short* __restrict__ ao) {
  __shared__ char SMEM[66560];  // 64KB: Qs 32K | Ks 2x8K | Vs 2x8K ; epilogue: Red 64K + LRed 1K
  unsigned short* Qs = (unsigned short*)SMEM;             // 256 x 64
  unsigned short* KsB = (unsigned short*)(SMEM + 32768);  // [2][64*64]
  unsigned short* VsB = (unsigned short*)(SMEM + 49152);  // [2][64*64]
  const int tid = threadIdx.x;                // 0..1023, 16 waves
  const int wave = tid >> 6, lane = tid & 63;
  const int row16 = lane & 15, quad = lane >> 4;
  const int rho = row16 & 7;
  const int kw = wave & 1, qw = wave >> 1;    // qw 0..7 owns q-rows [qw*32, qw*32+32)
  const int bh = blockIdx.x;                  // XCD = id%8 = bh%8 (keeps R6 FETCH win)
  const int b = bh >> 3, h = bh & 7;
  const int q0 = blockIdx.y * 256;

  const char* qg = (const char*)(qb + ((size_t)bh * NTOK + q0) * DH);
  const char* kgb = (const char*)(kb + (size_t)bh * NTOK * DH);
  const char* vgb = (const char*)(vtb + (size_t)bh * DH * NTOK);

  const int half = tid >> 9;             // 0: this wave stages K, 1: stages V
  const int stid = tid & 511;
  const int sr = stid >> 3;              // 0..63 staging row
  const int sc = (stid & 7) ^ (sr & 7);  // swizzled source chunk

  // prologue: Q (2048 chunks / 1024 threads) + K/V tile 0 (1 chunk/thread)
#pragma unroll
  for (int i = 0; i < 2; i++) {
    int idx = i * 1024 + tid;
    int r = idx >> 3;
    int c = (idx & 7) ^ (r & 7);
    gl2lds16(qg + r * 128 + c * 16, SMEM + idx * 16);
  }
  if (half == 0)
    gl2lds16(kgb + sr * 128 + sc * 16, (char*)KsB + stid * 16);
  else
    gl2lds16(vgb + (size_t)sr * 4096 + sc * 16, (char*)VsB + stid * 16);
  __syncthreads();

  bf16x8 aq[2][2];
#pragma unroll
  for (int qs = 0; qs < 2; qs++) {
    const int qrow = qw * 32 + qs * 16 + row16;
#pragma unroll
    for (int ki = 0; ki < 2; ki++)
      aq[qs][ki] = *(const bf16x8*)&Qs[qrow * 64 + (((ki * 4 + quad) ^ rho) * 8)];
  }

  f32x4 accT[4][2] = {};  // O^T frags: [d-group][q-group], this wave's 32 keys only
  float lsum[2] = {0.f, 0.f};
  const float cs = 0.125f * 1.44269504088896f;
  const float c0 = mlab[b * 4 + 0] ? -16.f : -100000.f;
  const float c1 = mlab[b * 4 + 1] ? -16.f : -100000.f;
  const float c2 = mlab[b * 4 + 2] ? -16.f : -100000.f;
  const float c3 = mlab[b * 4 + 3] ? -16.f : -100000.f;

  for (int t = 0; t < 32; t++) {
    const int buf = t & 1;
    if (t < 31) {
      if (half == 0)
        gl2lds16(kgb + (size_t)(t + 1) * 8192 + sr * 128 + sc * 16,
                 (char*)KsB + (buf ^ 1) * 8192 + stid * 16);
      else
        gl2lds16(vgb + (size_t)(t + 1) * 128 + (size_t)sr * 4096 + sc * 16,
                 (char*)VsB + (buf ^ 1) * 8192 + stid * 16);
    }
    // S'[key][q] for this wave's 32 keys (kw half): A = K frag, B = Q frag
    f32x4 S[2][2];
#pragma unroll
    for (int f = 0; f < 2; f++) {
      const unsigned short* Kr = KsB + buf * 4096 + (kw * 32 + f * 16 + row16) * 64;
      bf16x8 ak0 = *(const bf16x8*)&Kr[(quad ^ rho) * 8];
      bf16x8 ak1 = *(const bf16x8*)&Kr[((quad + 4) ^ rho) * 8];
#pragma unroll
      for (int qs = 0; qs < 2; qs++) {
        f32x4 z = {};
        z = MFMA16(ak0, aq[qs][0], z);
        z = MFMA16(ak1, aq[qs][1], z);
        S[qs][f] = z;
      }
    }
    const int mi = t >> 3;
    const float c = (mi == 0) ? c0 : (mi == 1) ? c1 : (mi == 2) ? c2 : c3;
    // P' = exp2(S'*cs + c); pack into K16 B-operand frags
    s16x4 pf[2][2];
#pragma unroll
    for (int qs = 0; qs < 2; qs++)
#pragma unroll
      for (int f = 0; f < 2; f++) {
        float p0 = fexp2(fmaf(S[qs][f][0], cs, c));
        float p1 = fexp2(fmaf(S[qs][f][1], cs, c));
        float p2 = fexp2(fmaf(S[qs][f][2], cs, c));
        float p3 = fexp2(fmaf(S[qs][f][3], cs, c));
        lsum[qs] += (p0 + p1) + (p2 + p3);
        uint2 pk;
        pk.x = packhi(p0, p1);
        pk.y = packhi(p2, p3);
        pf[qs][f] = *(s16x4*)&pk;
      }
    // O^T += V^T · P' over this wave's 32 keys
#pragma unroll
    for (int g = 0; g < 4; g++) {
      const unsigned short* Vr = VsB + buf * 4096 + (g * 16 + row16) * 64;
#pragma unroll
      for (int u = 0; u < 2; u++) {
        s16x4 va = *(const s16x4*)&Vr[(((kw * 4 + 2 * u + (quad >> 1)) ^ rho) * 8) + (quad & 1) * 4];
#pragma unroll
        for (int qs = 0; qs < 2; qs++) accT[g][qs] = MFMAK16(va, pf[qs][u], accT[g][qs]);
      }
    }
    __syncthreads();
  }

  // quad-combine lsum within wave (covers this wave's 32 keys; value per q = qs*16+row16)
#pragma unroll
  for (int qs = 0; qs < 2; qs++) {
    float s = lsum[qs];
    s += __shfl_xor(s, 16, 64);
    s += __shfl_xor(s, 32, 64);
    lsum[qs] = s;
  }

  // cross-wave (kw-pair) reduction through LDS. All K/V/Q data dead; reuse SMEM.
  float* Red = (float*)SMEM;             // 8 regions x 2048 floats (8KB per qw)
  float* LRed = (float*)(SMEM + 65536);  // 8 x 32 floats
  if (kw) {
    float* R = Red + qw * 2048;
#pragma unroll
    for (int g = 0; g < 4; g++)
#pragma unroll
      for (int qs = 0; qs < 2; qs++) {
        int c2 = (g * 2 + qs) ^ (lane & 7);
        *(f32x4*)&R[lane * 32 + c2 * 4] = accT[g][qs];
      }
    if (quad == 0)
#pragma unroll
      for (int qs = 0; qs < 2; qs++) LRed[qw * 32 + qs * 16 + row16] = lsum[qs];
  }
  __syncthreads();
  if (kw == 0) {
    float* R = Red + qw * 2048;
#pragma unroll
    for (int g = 0; g < 4; g++)
#pragma unroll
      for (int qs = 0; qs < 2; qs++) {
        int c2 = (g * 2 + qs) ^ (lane & 7);
        f32x4 o = *(const f32x4*)&R[lane * 32 + c2 * 4];
        accT[g][qs] += o;
      }
    float inv[2];
#pragma unroll
    for (int qs = 0; qs < 2; qs++)
      inv[qs] = 1.0f / (lsum[qs] + LRed[qw * 32 + qs * 16 + row16]);
#pragma unroll
    for (int qs = 0; qs < 2; qs++) {
      const int q = q0 + qw * 32 + qs * 16 + row16;
      unsigned short* aor = ao + ((size_t)b * NTOK + q) * DIMD + h * DH;
#pragma unroll
      for (int g = 0; g < 4; g++) {
        *(unsigned*)&aor[g * 16 + quad * 4] = packhi(accT[g][qs][0] * inv[qs], accT[g][qs][1] * inv[qs]);
        *(unsigned*)&aor[g * 16 + quad * 4 + 2] = packhi(accT[g][qs][2] * inv[qs], accT[g][qs][3] * inv[qs]);
      }
    }
  }
}

// ---------------- out GEMM: 128x64 tile, DMA dbuf, fp32 out + bias ----------------
__global__ __launch_bounds__(256, 2) void out_gemm(const unsigned short* __restrict__ A,
                                                   const unsigned short* __restrict__ Bt,
                                                   const float* __restrict__ bias,
                                                   float* __restrict__ out) {
  __shared__ unsigned short As[2][128 * 64];
  __shared__ unsigned short Bs[2][64 * 64];
  const int tid = threadIdx.x;
  const int wave = tid >> 6, lane = tid & 63;
  const int row16 = lane & 15, quad = lane >> 4;
  const int rho = row16 & 7;
  const int m0 = blockIdx.x * 128;
  const int n0 = blockIdx.y * 64;
  const int rw = (wave & 1) * 64, cw = (wave >> 1) * 32;

  const char* Ab = (const char*)A;
  const char* Bb = (const char*)Bt;
#pragma unroll
  for (int i = 0; i < 4; i++) {
    int idx = i * 256 + tid;
    int r = idx >> 3;
    int c = (idx & 7) ^ (r & 7);
    gl2lds16(Ab + ((size_t)(m0 + r) * DIMD) * 2 + c * 16, (char*)As[0] + idx * 16);
  }
#pragma unroll
  for (int i = 0; i < 2; i++) {
    int idx = i * 256 + tid;
    int r = idx >> 3;
    int c = (idx & 7) ^ (r & 7);
    gl2lds16(Bb + ((size_t)(n0 + r) * DIMD) * 2 + c * 16, (char*)Bs[0] + idx * 16);
  }
  __syncthreads();

  f32x4 acc[4][2] = {};
  for (int kt = 0; kt < 8; kt++) {
    const int buf = kt & 1;
    if (kt < 7) {
      const int k0 = (kt + 1) * 64;
#pragma unroll
      for (int i = 0; i < 4; i++) {
        int idx = i * 256 + tid;
        int r = idx >> 3;
        int c = (idx & 7) ^ (r & 7);
        gl2lds16(Ab + ((size_t)(m0 + r) * DIMD + k0) * 2 + c * 16, (char*)As[buf ^ 1] + idx * 16);
      }
#pragma unroll
      for (int i = 0; i < 2; i++) {
        int idx = i * 256 + tid;
        int r = idx >> 3;
        int c = (idx & 7) ^ (r & 7);
        gl2lds16(Bb + ((size_t)(n0 + r) * DIMD + k0) * 2 + c * 16, (char*)Bs[buf ^ 1] + idx * 16);
      }
    }
#pragma unroll
    for (int ks = 0; ks < 2; ks++) {
      bf16x8 av[4], bv[2];
#pragma unroll
      for (int i = 0; i < 4; i++)
        av[i] = *(const bf16x8*)&As[buf][(rw + i * 16 + row16) * 64 + (((ks * 4 + quad) ^ rho) * 8)];
#pragma unroll
      for (int j = 0; j < 2; j++)
        bv[j] = *(const bf16x8*)&Bs[buf][(cw + j * 16 + row16) * 64 + (((ks * 4 + quad) ^ rho) * 8)];
#pragma unroll
      for (int i = 0; i < 4; i++)
#pragma unroll
        for (int j = 0; j < 2; j++) acc[i][j] = MFMA16(av[i], bv[j], acc[i][j]);
    }
    __syncthreads();
  }

#pragma unroll
  for (int j = 0; j < 2; j++) {
    const int col = n0 + cw + j * 16 + row16;
    const float bv = bias[col];
#pragma unroll
    for (int i = 0; i < 4; i++)
#pragma unroll
      for (int r = 0; r < 4; r++) {
        const int row = m0 + rw + i * 16 + quad * 4 + r;
        out[(size_t)row * DIMD + col] = acc[i][j][r] + bv;
      }
  }
}

extern "C" void kernel_launch(void* const* d_in, const int* in_sizes, int n_in,
                              void* d_out, int out_size, void* d_ws, size_t ws_size,
                              hipStream_t stream) {
  const float* x = (const float*)d_in[0];
  const int* mlab = (const int*)d_in[1];
  const float* gamma = (const float*)d_in[2];
  const float* beta = (const float*)d_in[3];
  const float* w_qkv = (const float*)d_in[4];
  const float* w_out = (const float*)d_in[5];
  const float* b_out = (const float*)d_in[6];
  float* out = (float*)d_out;

  char* ws = (char*)d_ws;
  unsigned short* xn = (unsigned short*)(ws);
  unsigned short* wqkvT = (unsigned short*)(ws + 8388608);
  unsigned short* woutT = (unsigned short*)(ws + 9961472);
  unsigned short* qbuf = (unsigned short*)(ws + 10485760);
  unsigned short* kbuf = (unsigned short*)(ws + 18874368);
  unsigned short* vtbuf = (unsigned short*)(ws + 27262976);
  unsigned short* aobuf = (unsigned short*)(ws + 35651584);

  prep_kernel<<<3072, 256, 0, stream>>>(x, gamma, beta, w_qkv, w_out, xn, wqkvT, woutT);
  qkv_gemm<<<dim3(64, 12), 256, 0, stream>>>(xn, wqkvT, qbuf, kbuf, vtbuf);
  attn_kernel<<<dim3(32, 8), 1024, 0, stream>>>(qbuf, kbuf, vtbuf, mlab, aobuf);
  out_gemm<<<dim3(64, 8), 256, 0, stream>>>(aobuf, woutT, b_out, out);
}

// Round 9
// 153.247 us; speedup vs baseline: 1.0720x; 1.0028x over previous
//
#include <hip/hip_runtime.h>

#define DIMD 512
#define NTOK 2048
#define HEADS 8
#define DH 64

typedef __attribute__((ext_vector_type(4))) float f32x4;
typedef __attribute__((ext_vector_type(8))) __bf16 bf16x8;
typedef __attribute__((ext_vector_type(4))) short s16x4;

#define MFMA16(a, b, c) __builtin_amdgcn_mfma_f32_16x16x32_bf16((a), (b), (c), 0, 0, 0)
#define MFMAK16(a, b, c) __builtin_amdgcn_mfma_f32_16x16x16bf16_1k((a), (b), (c), 0, 0, 0)

__device__ __forceinline__ unsigned short f2bf(float f) {
  unsigned int u = __float_as_uint(f);
  u += 0x7fffu + ((u >> 16) & 1u);
  return (unsigned short)(u >> 16);
}

// raw hardware exp2: one v_exp_f32 (OCML exp2f is a multi-instr denorm-guarded
// sequence without -ffast-math — measured as the dominant attn VALU cost).
// Inputs here are <= -15 (live) or ~-1e5 (masked -> underflows to +0). Both exact.
__device__ __forceinline__ float fexp2(float x) {
  float r;
  asm("v_exp_f32 %0, %1" : "=v"(r) : "v"(x));
  return r;
}

// pack truncated bf16(b) into low short, bf16(a) into high short
__device__ __forceinline__ unsigned packhi(float b, float a) {
#if __has_builtin(__builtin_amdgcn_perm)
  return __builtin_amdgcn_perm(__float_as_uint(a), __float_as_uint(b), 0x07060302u);
#else
  return (__float_as_uint(b) >> 16) | (__float_as_uint(a) & 0xffff0000u);
#endif
}

// async global->LDS, 16B per lane; LDS dest = wave base + lane*16 (contiguous).
__device__ __forceinline__ void gl2lds16(const void* g, void* l) {
  auto gp = reinterpret_cast<__attribute__((address_space(1))) unsigned int*>(
      reinterpret_cast<unsigned long long>(g));
  auto lp = reinterpret_cast<__attribute__((address_space(3))) unsigned int*>(
      reinterpret_cast<unsigned long long>(l));
  __builtin_amdgcn_global_load_lds(gp, lp, 16, 0, 0);
}

// ---------------- prep: LN(bid<2048) + w_qkv transpose + w_out transpose ----------------
__global__ __launch_bounds__(256) void prep_kernel(const float* __restrict__ x,
                                                   const float* __restrict__ gamma,
                                                   const float* __restrict__ beta,
                                                   const float* __restrict__ w_qkv,
                                                   const float* __restrict__ w_out,
                                                   unsigned short* __restrict__ xn,
                                                   unsigned short* __restrict__ wqkvT,
                                                   unsigned short* __restrict__ woutT) {
  __shared__ float t[32][33];
  const int bid = blockIdx.x;
  if (bid < 2048) {
    const int row = bid * 4 + (threadIdx.x >> 6);
    const int lane = threadIdx.x & 63;
    const float4* xr = (const float4*)(x + (size_t)row * DIMD);
    float4 a = xr[lane];
    float4 b = xr[lane + 64];
    float s = a.x + a.y + a.z + a.w + b.x + b.y + b.z + b.w;
    for (int off = 1; off < 64; off <<= 1) s += __shfl_xor(s, off, 64);
    float mu = s * (1.0f / DIMD);
    float d0 = a.x - mu, d1 = a.y - mu, d2 = a.z - mu, d3 = a.w - mu;
    float e0 = b.x - mu, e1 = b.y - mu, e2 = b.z - mu, e3 = b.w - mu;
    float v = d0 * d0 + d1 * d1 + d2 * d2 + d3 * d3 + e0 * e0 + e1 * e1 + e2 * e2 + e3 * e3;
    for (int off = 1; off < 64; off <<= 1) v += __shfl_xor(v, off, 64);
    float rs = rsqrtf(v * (1.0f / DIMD) + 1e-5f);
    const float4* g4 = (const float4*)gamma;
    const float4* be4 = (const float4*)beta;
    float4 ga = g4[lane], gb = g4[lane + 64];
    float4 ba = be4[lane], bb = be4[lane + 64];
    unsigned p0 = (unsigned)f2bf(d0 * rs * ga.x + ba.x) | ((unsigned)f2bf(d1 * rs * ga.y + ba.y) << 16);
    unsigned p1 = (unsigned)f2bf(d2 * rs * ga.z + ba.z) | ((unsigned)f2bf(d3 * rs * ga.w + ba.w) << 16);
    unsigned p2 = (unsigned)f2bf(e0 * rs * gb.x + bb.x) | ((unsigned)f2bf(e1 * rs * gb.y + bb.y) << 16);
    unsigned p3 = (unsigned)f2bf(e2 * rs * gb.z + bb.z) | ((unsigned)f2bf(e3 * rs * gb.w + bb.w) << 16);
    uint2 w0; w0.x = p0; w0.y = p1;
    uint2 w1; w1.x = p2; w1.y = p3;
    *(uint2*)&xn[(size_t)row * DIMD + lane * 4] = w0;
    *(uint2*)&xn[(size_t)row * DIMD + 256 + lane * 4] = w1;
  } else {
    const float* w;
    unsigned short* wt;
    int C, bx, by;
    if (bid < 2816) { w = w_qkv; wt = wqkvT; C = 1536; bx = (bid - 2048) % 48; by = (bid - 2048) / 48; }
    else            { w = w_out; wt = woutT; C = 512;  bx = (bid - 2816) % 16; by = (bid - 2816) / 16; }
    const int R = 512;
    int tx = threadIdx.x & 31, ty = threadIdx.x >> 5;
    int c0 = bx * 32, r0 = by * 32;
    for (int i = 0; i < 4; i++)
      t[ty + 8 * i][tx] = w[(size_t)(r0 + ty + 8 * i) * C + c0 + tx];
    __syncthreads();
    for (int i = 0; i < 4; i++)
      wt[(size_t)(c0 + ty + 8 * i) * R + r0 + tx] = f2bf(t[tx][ty + 8 * i]);
  }
}

// ---------------- QKV GEMM: 128x128 tile, BK=64, swizzled DMA dbuf ----------------
__global__ __launch_bounds__(256, 2) void qkv_gemm(const unsigned short* __restrict__ A,
                                                   const unsigned short* __restrict__ Bt,
                                                   unsigned short* __restrict__ qb,
                                                   unsigned short* __restrict__ kb,
                                                   unsigned short* __restrict__ vtb) {
  __shared__ unsigned short As[2][128 * 64];
  __shared__ unsigned short Bs[2][128 * 64];
  const int tid = threadIdx.x;
  const int wave = tid >> 6, lane = tid & 63;
  const int row16 = lane & 15, quad = lane >> 4;
  const int rho = row16 & 7;
  const int m0 = blockIdx.x * 128;
  const int n0 = blockIdx.y * 128;
  const int rw = (wave & 1) * 64, cw = (wave >> 1) * 64;

  const char* Ab = (const char*)A;
  const char* Bb = (const char*)Bt;
#pragma unroll
  for (int i = 0; i < 4; i++) {
    int idx = i * 256 + tid;
    int r = idx >> 3;
    int c = (idx & 7) ^ (r & 7);
    gl2lds16(Ab + ((size_t)(m0 + r) * DIMD) * 2 + c * 16, (char*)As[0] + idx * 16);
    gl2lds16(Bb + ((size_t)(n0 + r) * DIMD) * 2 + c * 16, (char*)Bs[0] + idx * 16);
  }
  __syncthreads();

  f32x4 acc[4][4] = {};
  for (int kt = 0; kt < 8; kt++) {
    const int buf = kt & 1;
    if (kt < 7) {
      const int k0 = (kt + 1) * 64;
#pragma unroll
      for (int i = 0; i < 4; i++) {
        int idx = i * 256 + tid;
        int r = idx >> 3;
        int c = (idx & 7) ^ (r & 7);
        gl2lds16(Ab + ((size_t)(m0 + r) * DIMD + k0) * 2 + c * 16, (char*)As[buf ^ 1] + idx * 16);
        gl2lds16(Bb + ((size_t)(n0 + r) * DIMD + k0) * 2 + c * 16, (char*)Bs[buf ^ 1] + idx * 16);
      }
    }
#pragma unroll
    for (int ks = 0; ks < 2; ks++) {
      bf16x8 av[4], bv[4];
#pragma unroll
      for (int i = 0; i < 4; i++) {
        int Ra = rw + i * 16 + row16;
        int Rb = cw + i * 16 + row16;
        av[i] = *(const bf16x8*)&As[buf][Ra * 64 + (((ks * 4 + quad) ^ rho) * 8)];
        bv[i] = *(const bf16x8*)&Bs[buf][Rb * 64 + (((ks * 4 + quad) ^ rho) * 8)];
      }
#pragma unroll
      for (int i = 0; i < 4; i++)
#pragma unroll
        for (int j = 0; j < 4; j++) acc[i][j] = MFMA16(av[i], bv[j], acc[i][j]);
    }
    __syncthreads();
  }

  unsigned short* Ct = (unsigned short*)As;
#pragma unroll
  for (int i = 0; i < 4; i++)
#pragma unroll
    for (int j = 0; j < 4; j++)
#pragma unroll
      for (int r = 0; r < 4; r++)
        Ct[(rw + i * 16 + quad * 4 + r) * 136 + cw + j * 16 + row16] = f2bf(acc[i][j][r]);
  __syncthreads();

  const int sect = n0 >> 9;
  const int h0 = (n0 & 511) >> 6;
  const int b = m0 >> 11;
  const int nbase = m0 & 2047;
  if (sect < 2) {
    unsigned short* dst = (sect == 0) ? qb : kb;
#pragma unroll
    for (int i = 0; i < 8; i++) {
      int cid = i * 256 + tid;
      int row = cid >> 4, col0 = (cid & 15) * 8;
      int h = h0 + (col0 >> 6), d0 = col0 & 63;
      uint4 val = *(const uint4*)&Ct[row * 136 + col0];
      *(uint4*)&dst[(((size_t)(b * HEADS + h) * NTOK) + nbase + row) * DH + d0] = val;
    }
  } else {
#pragma unroll
    for (int u = 0; u < 4; u++) {
      int uid = u * 256 + tid;
      int col = uid >> 3, rc = (uid & 7) * 16;
      int h = h0 + (col >> 6), d = col & 63;
      unsigned short tmp[16];
#pragma unroll
      for (int j = 0; j < 16; j++) tmp[j] = Ct[(rc + j) * 136 + col];
      size_t base = ((size_t)(b * HEADS + h) * DH + d) * NTOK + nbase + rc;
      *(uint4*)&vtb[base] = *(uint4*)&tmp[0];
      *(uint4*)&vtb[base + 8] = *(uint4*)&tmp[8];
    }
  }
}

// ---------------- attention: q-tile 256 (8 waves), hoisted-address + static-buf loop ----------------
// R8 proved the kernel is not latency/TLP-bound and not LDS/HBM-bound. Measured
// VALUBusy = ~1790 cyc/SIMD/tile vs ~400 essential -> the cost is rematerialized
// swizzled LDS addressing (VGPR was squeezed to 56-64) + dependent-MFMA stalls.
// This version: (1) 6 lane-swizzled base pointers hoisted out of the loop;
// (2) t-loop unrolled x2 so buf is compile-time and every LDS read is base+immediate;
// (3) global prefetch via two bumped pointers; (4) QK as two 8-independent MFMA
// passes; PV u-outer/g-inner (dependent ops 8 issues apart); (5) (512,2) bounds.
__global__ __launch_bounds__(512, 2) void attn_kernel(const unsigned short* __restrict__ qb,
                                                      const unsigned short* __restrict__ kb,
                                                      const unsigned short* __restrict__ vtb,
                                                      const int* __restrict__ mlab,
                                                      unsigned short* __restrict__ ao) {
  __shared__ unsigned short Qs[256 * 64];     // 32KB
  __shared__ unsigned short Ks[2][64 * 64];   // 16KB
  __shared__ unsigned short Vs[2][64 * 64];   // 16KB
  const int tid = threadIdx.x;
  const int wave = tid >> 6, lane = tid & 63;
  const int row16 = lane & 15, quad = lane >> 4;
  const int rho = row16 & 7;
  const int bh = blockIdx.x;              // XCD = id%8 = bh%8 (keeps R6 FETCH win)
  const int b = bh >> 3, h = bh & 7;
  const int q0 = blockIdx.y * 256;

  const char* qg = (const char*)(qb + ((size_t)bh * NTOK + q0) * DH);
  const char* kgb = (const char*)(kb + (size_t)bh * NTOK * DH);
  const char* vgb = (const char*)(vtb + (size_t)bh * DH * NTOK);
  const int sr = tid >> 3;              // 0..63 staging row
  const int sc = (tid & 7) ^ (sr & 7);  // swizzled source chunk

  // prologue: Q (256 rows) + K/V tile 0
#pragma unroll
  for (int i = 0; i < 4; i++)
    gl2lds16(qg + (sr + 64 * i) * 128 + sc * 16, (char*)Qs + tid * 16 + i * 8192);
  gl2lds16(kgb + sr * 128 + sc * 16, (char*)Ks[0] + tid * 16);
  gl2lds16(vgb + (size_t)sr * 4096 + sc * 16, (char*)Vs[0] + tid * 16);
  __syncthreads();

  // wave owns q-rows [wave*32, wave*32+32)
  bf16x8 aq[2][2];
#pragma unroll
  for (int qs = 0; qs < 2; qs++) {
    const int qrow = wave * 32 + qs * 16 + row16;
#pragma unroll
    for (int ki = 0; ki < 2; ki++)
      aq[qs][ki] = *(const bf16x8*)&Qs[qrow * 64 + (((ki * 4 + quad) ^ rho) * 8)];
  }

  // hoisted lane-swizzled LDS base pointers (buf0); buf and f/g strides are immediates
  const char* Kbase = (const char*)Ks[0] + row16 * 128;
  const char* K0 = Kbase + ((quad ^ rho) * 16);
  const char* K1 = Kbase + (((quad + 4) ^ rho) * 16);
  const char* Vbase = (const char*)Vs[0] + row16 * 128;
  const char* V0 = Vbase + (((0 + (quad >> 1)) ^ rho) * 16 + (quad & 1) * 8);
  const char* V1 = Vbase + (((2 + (quad >> 1)) ^ rho) * 16 + (quad & 1) * 8);
  const char* V2 = Vbase + (((4 + (quad >> 1)) ^ rho) * 16 + (quad & 1) * 8);
  const char* V3 = Vbase + (((6 + (quad >> 1)) ^ rho) * 16 + (quad & 1) * 8);

  // bumped global prefetch pointers (next tile = 1)
  const char* kp = kgb + 8192 + sr * 128 + sc * 16;
  const char* vp = vgb + 128 + (size_t)sr * 4096 + sc * 16;

  f32x4 accT[4][2] = {};  // O^T frags: [d-group][q-group]
  float lsum[2] = {0.f, 0.f};
  const float cs = 0.125f * 1.44269504088896f;
  const float c0 = mlab[b * 4 + 0] ? -16.f : -100000.f;
  const float c1 = mlab[b * 4 + 1] ? -16.f : -100000.f;
  const float c2 = mlab[b * 4 + 2] ? -16.f : -100000.f;
  const float c3 = mlab[b * 4 + 3] ? -16.f : -100000.f;

  for (int tt = 0; tt < 16; tt++) {
#pragma unroll
    for (int hf = 0; hf < 2; hf++) {
      const int t = tt * 2 + hf;
      const int B = hf * 8192;        // current buf byte offset (compile-time)
      const int Bn = (hf ^ 1) * 8192; // prefetch buf byte offset (compile-time)
      if (t < 31) {
        gl2lds16(kp, (char*)Ks[0] + Bn + tid * 16);
        gl2lds16(vp, (char*)Vs[0] + Bn + tid * 16);
        kp += 8192;
        vp += 128;
      }
      // QK: load all 8 K frags, then two passes of 8 independent MFMAs
      bf16x8 ak0[4], ak1[4];
#pragma unroll
      for (int f = 0; f < 4; f++) {
        ak0[f] = *(const bf16x8*)(K0 + B + f * 2048);
        ak1[f] = *(const bf16x8*)(K1 + B + f * 2048);
      }
      f32x4 S[2][4];
#pragma unroll
      for (int f = 0; f < 4; f++)
#pragma unroll
        for (int qs = 0; qs < 2; qs++) {
          f32x4 z = {};
          S[qs][f] = MFMA16(ak0[f], aq[qs][0], z);
        }
#pragma unroll
      for (int f = 0; f < 4; f++)
#pragma unroll
        for (int qs = 0; qs < 2; qs++)
          S[qs][f] = MFMA16(ak1[f], aq[qs][1], S[qs][f]);

      const int mi = t >> 3;
      const float c = (mi == 0) ? c0 : (mi == 1) ? c1 : (mi == 2) ? c2 : c3;
      // P' = exp2(S'*cs + c) via raw v_exp_f32; pack into K16 B-operand frags
      s16x4 pf[2][4];
#pragma unroll
      for (int qs = 0; qs < 2; qs++)
#pragma unroll
        for (int f = 0; f < 4; f++) {
          float p0 = fexp2(fmaf(S[qs][f][0], cs, c));
          float p1 = fexp2(fmaf(S[qs][f][1], cs, c));
          float p2 = fexp2(fmaf(S[qs][f][2], cs, c));
          float p3 = fexp2(fmaf(S[qs][f][3], cs, c));
          lsum[qs] += (p0 + p1) + (p2 + p3);
          uint2 pk;
          pk.x = packhi(p0, p1);
          pk.y = packhi(p2, p3);
          pf[qs][f] = *(s16x4*)&pk;
        }
      // O^T += V^T · P' : u outer, g inner -> dependent ops on accT[g][qs] 8 apart
#pragma unroll
      for (int u = 0; u < 4; u++) {
        const char* Vu = (u == 0 ? V0 : u == 1 ? V1 : u == 2 ? V2 : V3) + B;
#pragma unroll
        for (int g = 0; g < 4; g++) {
          s16x4 va = *(const s16x4*)(Vu + g * 2048);
#pragma unroll
          for (int qs = 0; qs < 2; qs++) accT[g][qs] = MFMAK16(va, pf[qs][u], accT[g][qs]);
        }
      }
      __syncthreads();
    }
  }

  // lane partial covers its quad's keys; combine across quads (q = qs*16+row16)
#pragma unroll
  for (int qs = 0; qs < 2; qs++) {
    float s = lsum[qs];
    s += __shfl_xor(s, 16, 64);
    s += __shfl_xor(s, 32, 64);
    lsum[qs] = 1.0f / s;
  }
#pragma unroll
  for (int qs = 0; qs < 2; qs++) {
    const int q = q0 + wave * 32 + qs * 16 + row16;
    unsigned short* aor = ao + ((size_t)b * NTOK + q) * DIMD + h * DH;
#pragma unroll
    for (int g = 0; g < 4; g++) {
      *(unsigned*)&aor[g * 16 + quad * 4] = packhi(accT[g][qs][0] * lsum[qs], accT[g][qs][1] * lsum[qs]);
      *(unsigned*)&aor[g * 16 + quad * 4 + 2] = packhi(accT[g][qs][2] * lsum[qs], accT[g][qs][3] * lsum[qs]);
    }
  }
}

// ---------------- out GEMM: 128x64 tile, DMA dbuf, fp32 out + bias ----------------
__global__ __launch_bounds__(256, 2) void out_gemm(const unsigned short* __restrict__ A,
                                                   const unsigned short* __restrict__ Bt,
                                                   const float* __restrict__ bias,
                                                   float* __restrict__ out) {
  __shared__ unsigned short As[2][128 * 64];
  __shared__ unsigned short Bs[2][64 * 64];
  const int tid = threadIdx.x;
  const int wave = tid >> 6, lane = tid & 63;
  const int row16 = lane & 15, quad = lane >> 4;
  const int rho = row16 & 7;
  const int m0 = blockIdx.x * 128;
  const int n0 = blockIdx.y * 64;
  const int rw = (wave & 1) * 64, cw = (wave >> 1) * 32;

  const char* Ab = (const char*)A;
  const char* Bb = (const char*)Bt;
#pragma unroll
  for (int i = 0; i < 4; i++) {
    int idx = i * 256 + tid;
    int r = idx >> 3;
    int c = (idx & 7) ^ (r & 7);
    gl2lds16(Ab + ((size_t)(m0 + r) * DIMD) * 2 + c * 16, (char*)As[0] + idx * 16);
  }
#pragma unroll
  for (int i = 0; i < 2; i++) {
    int idx = i * 256 + tid;
    int r = idx >> 3;
    int c = (idx & 7) ^ (r & 7);
    gl2lds16(Bb + ((size_t)(n0 + r) * DIMD) * 2 + c * 16, (char*)Bs[0] + idx * 16);
  }
  __syncthreads();

  f32x4 acc[4][2] = {};
  for (int kt = 0; kt < 8; kt++) {
    const int buf = kt & 1;
    if (kt < 7) {
      const int k0 = (kt + 1) * 64;
#pragma unroll
      for (int i = 0; i < 4; i++) {
        int idx = i * 256 + tid;
        int r = idx >> 3;
        int c = (idx & 7) ^ (r & 7);
        gl2lds16(Ab + ((size_t)(m0 + r) * DIMD + k0) * 2 + c * 16, (char*)As[buf ^ 1] + idx * 16);
      }
#pragma unroll
      for (int i = 0; i < 2; i++) {
        int idx = i * 256 + tid;
        int r = idx >> 3;
        int c = (idx & 7) ^ (r & 7);
        gl2lds16(Bb + ((size_t)(n0 + r) * DIMD + k0) * 2 + c * 16, (char*)Bs[buf ^ 1] + idx * 16);
      }
    }
#pragma unroll
    for (int ks = 0; ks < 2; ks++) {
      bf16x8 av[4], bv[2];
#pragma unroll
      for (int i = 0; i < 4; i++)
        av[i] = *(const bf16x8*)&As[buf][(rw + i * 16 + row16) * 64 + (((ks * 4 + quad) ^ rho) * 8)];
#pragma unroll
      for (int j = 0; j < 2; j++)
        bv[j] = *(const bf16x8*)&Bs[buf][(cw + j * 16 + row16) * 64 + (((ks * 4 + quad) ^ rho) * 8)];
#pragma unroll
      for (int i = 0; i < 4; i++)
#pragma unroll
        for (int j = 0; j < 2; j++) acc[i][j] = MFMA16(av[i], bv[j], acc[i][j]);
    }
    __syncthreads();
  }

#pragma unroll
  for (int j = 0; j < 2; j++) {
    const int col = n0 + cw + j * 16 + row16;
    const float bv = bias[col];
#pragma unroll
    for (int i = 0; i < 4; i++)
#pragma unroll
      for (int r = 0; r < 4; r++) {
        const int row = m0 + rw + i * 16 + quad * 4 + r;
        out[(size_t)row * DIMD + col] = acc[i][j][r] + bv;
      }
  }
}

extern "C" void kernel_launch(void* const* d_in, const int* in_sizes, int n_in,
                              void* d_out, int out_size, void* d_ws, size_t ws_size,
                              hipStream_t stream) {
  const float* x = (const float*)d_in[0];
  const int* mlab = (const int*)d_in[1];
  const float* gamma = (const float*)d_in[2];
  const float* beta = (const float*)d_in[3];
  const float* w_qkv = (const float*)d_in[4];
  const float* w_out = (const float*)d_in[5];
  const float* b_out = (const float*)d_in[6];
  float* out = (float*)d_out;

  char* ws = (char*)d_ws;
  unsigned short* xn = (unsigned short*)(ws);
  unsigned short* wqkvT = (unsigned short*)(ws + 8388608);
  unsigned short* woutT = (unsigned short*)(ws + 9961472);
  unsigned short* qbuf = (unsigned short*)(ws + 10485760);
  unsigned short* kbuf = (unsigned short*)(ws + 18874368);
  unsigned short* vtbuf = (unsigned short*)(ws + 27262976);
  unsigned short* aobuf = (unsigned short*)(ws + 35651584);

  prep_kernel<<<3072, 256, 0, stream>>>(x, gamma, beta, w_qkv, w_out, xn, wqkvT, woutT);
  qkv_gemm<<<dim3(64, 12), 256, 0, stream>>>(xn, wqkvT, qbuf, kbuf, vtbuf);
  attn_kernel<<<dim3(32, 8), 512, 0, stream>>>(qbuf, kbuf, vtbuf, mlab, aobuf);
  out_gemm<<<dim3(64, 8), 256, 0, stream>>>(aobuf, woutT, b_out, out);
}